// Round 8
// baseline (317.196 us; speedup 1.0000x reference)
//
#include <hip/hip_runtime.h>
#include <hip/hip_cooperative_groups.h>

namespace cg = cooperative_groups;

// Problem constants (from reference): B=16, C=1, H=1024, W=1024, fp32.
#define HH 1024
#define WW 1024
#define BAND 16          // rows per block; thread = 16 rows x float4 strip
#define NT 256
#define NBLK ((HH / BAND) * 16)   // 1024 blocks (B=16)

// ext_vector type so __builtin_nontemporal_load accepts it.
typedef __attribute__((ext_vector_type(4))) float f32x4;

__device__ __forceinline__ float fmax3(float a, float b, float c) {
    return fmaxf(a, fmaxf(b, c));
}

__device__ __forceinline__ float loss_elem(float x, float t, float dil) {
    // target/dilated are exactly binary {0,1}: weight = 1 + 4*dil + 15*t
    float w = fmaf(15.0f, t, fmaf(4.0f, dil, 1.0f));
    // BCE with logits: max(x,0) - x*t + log1p(exp(-|x|))
    float a  = fabsf(x);
    float sp = __logf(1.0f + __expf(-a));
    return w * (fmaxf(x, 0.0f) - x * t + sp);
}

// R17: R16 (BAND=16 nt burst + LDS boundary exchange; main ~36.5us,
//   3.65 TB/s vs the ~3.8 TB/s per-CU service-rate cap measured across all
//   configs) + SINGLE-KERNEL FUSION via cooperative launch.
//   The reduce dispatch (1 block, 16KB) + inter-kernel gap is ~5-8us of the
//   measured window — bigger than all remaining main-side byte headroom
//   (133MB issued vs 128MB floor = ~2-3us). Fuse: each block writes ONE
//   deterministic partial, grid.sync(), block 0 sums 1024 partials in fixed
//   order (bitwise-stable, no float atomics), writes out.
//   Co-residency: 1024 blocks = 4 blocks/CU = 16 waves/CU -> waves_per_eu(4,4)
//   pins a 128-VGPR budget (R16 used 104 -> fits; the spilling rounds all had
//   RANGE attrs targeting 8 waves/64 VGPR).
//   Decision: WRITE_SIZE in MBs => spill under (4,4) => revert to R16.
//             coop-launch error / absmax!=0 => revert to R16, declare roofline.
__global__ __launch_bounds__(NT)
__attribute__((amdgpu_waves_per_eu(4, 4)))
void dilatedweightBCE_fused(
        const float* __restrict__ pred,
        const float* __restrict__ target,
        float* __restrict__ partial,
        float* __restrict__ out,
        float inv_n) {
    __shared__ float swave[NT / 64];
    __shared__ float ldsL[NT / 64][BAND];   // vm.x of lane0 of each wave
    __shared__ float ldsR[NT / 64][BAND];   // vm.w of lane63 of each wave

    const int t    = threadIdx.x;
    const int lane = t & 63;
    const int wv   = t >> 6;
    const int c    = t * 4;                  // column strip (NT*4 == WW)

    // --- XCD-contiguous swizzle: l -> (img, h0) ---
    const int l    = blockIdx.x;             // [0, 1024)
    const int xcd  = l & 7;
    const int j    = l >> 3;                 // [0, 128)
    const int img  = j >> 3;                 // [0, 16)
    const int slab = j & 7;                  // [0, 8)
    const int h0   = (xcd * 8 + slab) * BAND;    // XCD x owns rows [128x,128x+128)

    const float* timg = target + (size_t)img * HH * WW;
    const float* pimg = pred   + (size_t)img * HH * WW;
    const f32x4 zero = (f32x4)(0.0f);

    // ---- ALL 34 independent loads issued before any use (nontemporal) ----
    f32x4 tr[BAND + 2];                     // target rows h0-1 .. h0+BAND
    tr[0] = (h0 > 0)
          ? __builtin_nontemporal_load((const f32x4*)(timg + (size_t)(h0 - 1) * WW + c))
          : zero;
    #pragma unroll
    for (int r = 0; r < BAND; ++r)
        tr[r + 1] = __builtin_nontemporal_load(
            (const f32x4*)(timg + (size_t)(h0 + r) * WW + c));
    tr[BAND + 1] = (h0 + BAND < HH)
          ? __builtin_nontemporal_load((const f32x4*)(timg + (size_t)(h0 + BAND) * WW + c))
          : zero;

    f32x4 xr[BAND];                         // pred rows h0 .. h0+BAND-1
    #pragma unroll
    for (int r = 0; r < BAND; ++r)
        xr[r] = __builtin_nontemporal_load(
            (const f32x4*)(pimg + (size_t)(h0 + r) * WW + c));

    // ---- wave-boundary column exchange via LDS (replaces halo loads) ----
    if (lane == 0) {
        #pragma unroll
        for (int r = 0; r < BAND; ++r)
            ldsL[wv][r] = fmax3(tr[r].x, tr[r + 1].x, tr[r + 2].x);
    }
    if (lane == 63) {
        #pragma unroll
        for (int r = 0; r < BAND; ++r)
            ldsR[wv][r] = fmax3(tr[r].w, tr[r + 1].w, tr[r + 2].w);
    }
    __syncthreads();

    // ---- dilation + loss, row by row (row j needs only tr[j..j+2]) ----
    float s = 0.0f;
    #pragma unroll
    for (int r = 0; r < BAND; ++r) {
        f32x4 a = tr[r], m = tr[r + 1], d = tr[r + 2];
        float vmx = fmax3(a.x, m.x, d.x);
        float vmy = fmax3(a.y, m.y, d.y);
        float vmz = fmax3(a.z, m.z, d.z);
        float vmw = fmax3(a.w, m.w, d.w);

        float lft = __shfl_up(vmw, 1);
        float rgt = __shfl_down(vmx, 1);
        if (lane == 0)  lft = (wv > 0)            ? ldsR[wv - 1][r] : 0.0f;
        if (lane == 63) rgt = (wv < NT / 64 - 1)  ? ldsL[wv + 1][r] : 0.0f;

        float d0 = fmax3(lft, vmx, vmy);
        float d1 = fmax3(vmx, vmy, vmz);
        float d2 = fmax3(vmy, vmz, vmw);
        float d3 = fmax3(vmz, vmw, rgt);

        f32x4 x = xr[r];
        s += loss_elem(x.x, m.x, d0);
        s += loss_elem(x.y, m.y, d1);
        s += loss_elem(x.z, m.z, d2);
        s += loss_elem(x.w, m.w, d3);
    }

    // ---- block reduction -> one deterministic partial per block ----
    #pragma unroll
    for (int off = 32; off > 0; off >>= 1)
        s += __shfl_down(s, off);
    if (lane == 0) swave[wv] = s;
    __syncthreads();
    if (t == 0)
        partial[l] = swave[0] + swave[1] + swave[2] + swave[3];

    // ---- grid-wide sync, block 0 finalizes (fixed order: bitwise-stable) ----
    cg::this_grid().sync();

    if (l == 0) {
        float v = partial[t] + partial[t + 256] + partial[t + 512] + partial[t + 768];
        #pragma unroll
        for (int off = 32; off > 0; off >>= 1)
            v += __shfl_down(v, off);
        if (lane == 0) swave[wv] = v;
        __syncthreads();
        if (t == 0)
            out[0] = (swave[0] + swave[1] + swave[2] + swave[3]) * inv_n;
    }
}

// ---------- fallback path (two-kernel, R16 structure) ----------
template <bool PER_WAVE>
__global__ __launch_bounds__(NT)
__attribute__((amdgpu_waves_per_eu(2, 2)))
void dilatedweightBCE_main(
        const float* __restrict__ pred,
        const float* __restrict__ target,
        float* __restrict__ partial) {
    __shared__ float swave[NT / 64];
    __shared__ float ldsL[NT / 64][BAND];
    __shared__ float ldsR[NT / 64][BAND];

    const int t    = threadIdx.x;
    const int lane = t & 63;
    const int wv   = t >> 6;
    const int c    = t * 4;

    const int l    = blockIdx.x;
    const int xcd  = l & 7;
    const int j    = l >> 3;
    const int img  = j >> 3;
    const int slab = j & 7;
    const int h0   = (xcd * 8 + slab) * BAND;

    const float* timg = target + (size_t)img * HH * WW;
    const float* pimg = pred   + (size_t)img * HH * WW;
    const f32x4 zero = (f32x4)(0.0f);

    f32x4 tr[BAND + 2];
    tr[0] = (h0 > 0)
          ? __builtin_nontemporal_load((const f32x4*)(timg + (size_t)(h0 - 1) * WW + c))
          : zero;
    #pragma unroll
    for (int r = 0; r < BAND; ++r)
        tr[r + 1] = __builtin_nontemporal_load(
            (const f32x4*)(timg + (size_t)(h0 + r) * WW + c));
    tr[BAND + 1] = (h0 + BAND < HH)
          ? __builtin_nontemporal_load((const f32x4*)(timg + (size_t)(h0 + BAND) * WW + c))
          : zero;

    f32x4 xr[BAND];
    #pragma unroll
    for (int r = 0; r < BAND; ++r)
        xr[r] = __builtin_nontemporal_load(
            (const f32x4*)(pimg + (size_t)(h0 + r) * WW + c));

    if (lane == 0) {
        #pragma unroll
        for (int r = 0; r < BAND; ++r)
            ldsL[wv][r] = fmax3(tr[r].x, tr[r + 1].x, tr[r + 2].x);
    }
    if (lane == 63) {
        #pragma unroll
        for (int r = 0; r < BAND; ++r)
            ldsR[wv][r] = fmax3(tr[r].w, tr[r + 1].w, tr[r + 2].w);
    }
    __syncthreads();

    float s = 0.0f;
    #pragma unroll
    for (int r = 0; r < BAND; ++r) {
        f32x4 a = tr[r], m = tr[r + 1], d = tr[r + 2];
        float vmx = fmax3(a.x, m.x, d.x);
        float vmy = fmax3(a.y, m.y, d.y);
        float vmz = fmax3(a.z, m.z, d.z);
        float vmw = fmax3(a.w, m.w, d.w);

        float lft = __shfl_up(vmw, 1);
        float rgt = __shfl_down(vmx, 1);
        if (lane == 0)  lft = (wv > 0)           ? ldsR[wv - 1][r] : 0.0f;
        if (lane == 63) rgt = (wv < NT / 64 - 1) ? ldsL[wv + 1][r] : 0.0f;

        float d0 = fmax3(lft, vmx, vmy);
        float d1 = fmax3(vmx, vmy, vmz);
        float d2 = fmax3(vmy, vmz, vmw);
        float d3 = fmax3(vmz, vmw, rgt);

        f32x4 x = xr[r];
        s += loss_elem(x.x, m.x, d0);
        s += loss_elem(x.y, m.y, d1);
        s += loss_elem(x.z, m.z, d2);
        s += loss_elem(x.w, m.w, d3);
    }

    #pragma unroll
    for (int off = 32; off > 0; off >>= 1)
        s += __shfl_down(s, off);

    if (PER_WAVE) {
        if (lane == 0)
            partial[(size_t)l * (NT / 64) + wv] = s;
    } else {
        if (lane == 0) swave[wv] = s;
        __syncthreads();
        if (t == 0) {
            float tot = 0.0f;
            #pragma unroll
            for (int i = 0; i < NT / 64; ++i) tot += swave[i];
            partial[l] = tot;
        }
    }
}

__global__ __launch_bounds__(1024) void dilatedweightBCE_reduce(
        const float* __restrict__ partial,
        float* __restrict__ out,
        int npart4,            // number of float4 chunks
        float inv_n) {
    __shared__ float swave[16];
    const int t = threadIdx.x;

    float s = 0.0f;
    const float4* p4 = (const float4*)partial;
    for (int i = t; i < npart4; i += 1024) {
        float4 v = p4[i];
        s += v.x + v.y + v.z + v.w;
    }

    #pragma unroll
    for (int off = 32; off > 0; off >>= 1)
        s += __shfl_down(s, off);

    const int lane = t & 63;
    if (lane == 0) swave[t >> 6] = s;
    __syncthreads();
    if (t == 0) {
        float tot = 0.0f;
        #pragma unroll
        for (int i = 0; i < 16; ++i) tot += swave[i];
        out[0] = tot * inv_n;
    }
}

extern "C" void kernel_launch(void* const* d_in, const int* in_sizes, int n_in,
                              void* d_out, int out_size, void* d_ws, size_t ws_size,
                              hipStream_t stream) {
    const float* pred   = (const float*)d_in[0];
    const float* target = (const float*)d_in[1];
    float* out     = (float*)d_out;
    float* partial = (float*)d_ws;

    const int n  = in_sizes[0];              // B*C*H*W
    float inv_n  = 1.0f / (float)n;

    // ---- primary: single cooperative kernel (main + reduce fused) ----
    void* kargs[] = { (void*)&pred, (void*)&target, (void*)&partial,
                      (void*)&out, (void*)&inv_n };
    hipError_t err = hipLaunchCooperativeKernel(
        (const void*)dilatedweightBCE_fused,
        dim3(NBLK), dim3(NT), kargs, 0, stream);

    if (err != hipSuccess) {
        // ---- fallback: R16 two-kernel path ----
        const int Bn = n / (HH * WW);
        const int nblocks = (HH / BAND) * Bn;
        const size_t need = (size_t)nblocks * (NT / 64) * sizeof(float);
        if (ws_size >= need) {
            dilatedweightBCE_main<true><<<nblocks, NT, 0, stream>>>(pred, target, partial);
            dilatedweightBCE_reduce<<<1, 1024, 0, stream>>>(partial, out,
                                                            nblocks * (NT / 64) / 4,
                                                            inv_n);
        } else {
            dilatedweightBCE_main<false><<<nblocks, NT, 0, stream>>>(pred, target, partial);
            dilatedweightBCE_reduce<<<1, 1024, 0, stream>>>(partial, out,
                                                            nblocks / 4,
                                                            inv_n);
        }
    }
}

// Round 9
// 139.756 us; speedup vs baseline: 2.2696x; 2.2696x over previous
//
#include <hip/hip_runtime.h>

// Problem constants (from reference): B=16, C=1, H=1024, W=1024, fp32.
#define HH 1024
#define WW 1024
#define BAND 16          // rows per block; thread = 16 rows x float4 strip
#define NT 256

// ext_vector type so __builtin_nontemporal_load accepts it.
typedef __attribute__((ext_vector_type(4))) float f32x4;

__device__ __forceinline__ float fmax3(float a, float b, float c) {
    return fmaxf(a, fmaxf(b, c));
}

__device__ __forceinline__ float loss_elem(float x, float t, float dil) {
    // target/dilated are exactly binary {0,1}: weight = 1 + 4*dil + 15*t
    float w = fmaf(15.0f, t, fmaf(4.0f, dil, 1.0f));
    // BCE with logits: max(x,0) - x*t + log1p(exp(-|x|))
    float a  = fabsf(x);
    float sp = __logf(1.0f + __expf(-a));
    return w * (fmaxf(x, 0.0f) - x * t + sp);
}

// R18: REVERT to R16 verbatim (best verified: total 140.2us, main ~36.5us).
//   R17 post-mortem: cooperative fusion spilled (VGPR=64 under
//   waves_per_eu(4,4) — attr didn't deliver the 128 budget on the coop
//   path) AND grid.sync() with 1024 blocks serialized to 196us. Reverted
//   per the pre-committed decision rule.
//   Session model (verified R12/R15/R16): nt reads stream pure-HBM at a
//   flat ~3.65-3.8 TB/s service-rate cap, independent of occupancy/burst
//   shape; issued bytes are the only lever. R16 issues 133MB vs the 128MB
//   unique floor; remaining main-side headroom ~3-5us (~3% of total) and
//   every candidate lever (two-phase BAND=32, reduce fusion) has already
//   regressed once this session. This is the keeper.
template <bool PER_WAVE>
__global__ __launch_bounds__(NT)
__attribute__((amdgpu_waves_per_eu(2, 2)))
void dilatedweightBCE_main(
        const float* __restrict__ pred,
        const float* __restrict__ target,
        float* __restrict__ partial) {
    __shared__ float swave[NT / 64];
    __shared__ float ldsL[NT / 64][BAND];   // vm.x of lane0 of each wave
    __shared__ float ldsR[NT / 64][BAND];   // vm.w of lane63 of each wave

    const int t    = threadIdx.x;
    const int lane = t & 63;
    const int wv   = t >> 6;
    const int c    = t * 4;                  // column strip (NT*4 == WW)

    // --- XCD-contiguous swizzle: l -> (img, h0) ---
    const int l    = blockIdx.x;             // [0, 1024)
    const int xcd  = l & 7;
    const int j    = l >> 3;                 // [0, 128)
    const int img  = j >> 3;                 // [0, 16)
    const int slab = j & 7;                  // [0, 8)
    const int h0   = (xcd * 8 + slab) * BAND;    // XCD x owns rows [128x,128x+128)

    const float* timg = target + (size_t)img * HH * WW;
    const float* pimg = pred   + (size_t)img * HH * WW;
    const f32x4 zero = (f32x4)(0.0f);

    // ---- ALL 34 independent loads issued before any use (nontemporal) ----
    f32x4 tr[BAND + 2];                     // target rows h0-1 .. h0+BAND
    tr[0] = (h0 > 0)
          ? __builtin_nontemporal_load((const f32x4*)(timg + (size_t)(h0 - 1) * WW + c))
          : zero;
    #pragma unroll
    for (int r = 0; r < BAND; ++r)
        tr[r + 1] = __builtin_nontemporal_load(
            (const f32x4*)(timg + (size_t)(h0 + r) * WW + c));
    tr[BAND + 1] = (h0 + BAND < HH)
          ? __builtin_nontemporal_load((const f32x4*)(timg + (size_t)(h0 + BAND) * WW + c))
          : zero;

    f32x4 xr[BAND];                         // pred rows h0 .. h0+BAND-1
    #pragma unroll
    for (int r = 0; r < BAND; ++r)
        xr[r] = __builtin_nontemporal_load(
            (const f32x4*)(pimg + (size_t)(h0 + r) * WW + c));

    // ---- wave-boundary column exchange via LDS (replaces halo loads) ----
    // lane0's left neighbor column (c-1) is lane63 of wave wv-1; lane63's
    // right neighbor (c+4) is lane0 of wave wv+1. Boundary lanes publish
    // their own column's 3-row vertical max for every row.
    if (lane == 0) {
        #pragma unroll
        for (int r = 0; r < BAND; ++r)
            ldsL[wv][r] = fmax3(tr[r].x, tr[r + 1].x, tr[r + 2].x);
    }
    if (lane == 63) {
        #pragma unroll
        for (int r = 0; r < BAND; ++r)
            ldsR[wv][r] = fmax3(tr[r].w, tr[r + 1].w, tr[r + 2].w);
    }
    __syncthreads();

    // ---- dilation + loss, row by row (row j needs only tr[j..j+2]) ----
    float s = 0.0f;
    #pragma unroll
    for (int r = 0; r < BAND; ++r) {
        f32x4 a = tr[r], m = tr[r + 1], d = tr[r + 2];
        float vmx = fmax3(a.x, m.x, d.x);
        float vmy = fmax3(a.y, m.y, d.y);
        float vmz = fmax3(a.z, m.z, d.z);
        float vmw = fmax3(a.w, m.w, d.w);

        float lft = __shfl_up(vmw, 1);
        float rgt = __shfl_down(vmx, 1);
        if (lane == 0)  lft = (wv > 0)            ? ldsR[wv - 1][r] : 0.0f;
        if (lane == 63) rgt = (wv < NT / 64 - 1)  ? ldsL[wv + 1][r] : 0.0f;

        float d0 = fmax3(lft, vmx, vmy);
        float d1 = fmax3(vmx, vmy, vmz);
        float d2 = fmax3(vmy, vmz, vmw);
        float d3 = fmax3(vmz, vmw, rgt);

        f32x4 x = xr[r];
        s += loss_elem(x.x, m.x, d0);
        s += loss_elem(x.y, m.y, d1);
        s += loss_elem(x.z, m.z, d2);
        s += loss_elem(x.w, m.w, d3);
    }

    // ---- wave reduction ----
    #pragma unroll
    for (int off = 32; off > 0; off >>= 1)
        s += __shfl_down(s, off);

    if (PER_WAVE) {
        if (lane == 0)
            partial[(size_t)l * (NT / 64) + wv] = s;   // no extra barrier
    } else {
        if (lane == 0) swave[wv] = s;
        __syncthreads();
        if (t == 0) {
            float tot = 0.0f;
            #pragma unroll
            for (int i = 0; i < NT / 64; ++i) tot += swave[i];
            partial[l] = tot;
        }
    }
}

__global__ __launch_bounds__(1024) void dilatedweightBCE_reduce(
        const float* __restrict__ partial,
        float* __restrict__ out,
        int npart4,            // number of float4 chunks
        float inv_n) {
    __shared__ float swave[16];
    const int t = threadIdx.x;

    float s = 0.0f;
    const float4* p4 = (const float4*)partial;
    for (int i = t; i < npart4; i += 1024) {
        float4 v = p4[i];
        s += v.x + v.y + v.z + v.w;
    }

    #pragma unroll
    for (int off = 32; off > 0; off >>= 1)
        s += __shfl_down(s, off);

    const int lane = t & 63;
    if (lane == 0) swave[t >> 6] = s;
    __syncthreads();
    if (t == 0) {
        float tot = 0.0f;
        #pragma unroll
        for (int i = 0; i < 16; ++i) tot += swave[i];
        out[0] = tot * inv_n;
    }
}

extern "C" void kernel_launch(void* const* d_in, const int* in_sizes, int n_in,
                              void* d_out, int out_size, void* d_ws, size_t ws_size,
                              hipStream_t stream) {
    const float* pred   = (const float*)d_in[0];
    const float* target = (const float*)d_in[1];
    float* out     = (float*)d_out;
    float* partial = (float*)d_ws;

    const int n  = in_sizes[0];              // B*C*H*W
    const int Bn = n / (HH * WW);            // batch (16)
    const int nblocks = (HH / BAND) * Bn;    // 1024

    const size_t need = (size_t)nblocks * (NT / 64) * sizeof(float);  // 16 KB
    if (ws_size >= need) {
        dilatedweightBCE_main<true><<<nblocks, NT, 0, stream>>>(pred, target, partial);
        dilatedweightBCE_reduce<<<1, 1024, 0, stream>>>(partial, out,
                                                        nblocks * (NT / 64) / 4,
                                                        1.0f / (float)n);
    } else {
        dilatedweightBCE_main<false><<<nblocks, NT, 0, stream>>>(pred, target, partial);
        dilatedweightBCE_reduce<<<1, 1024, 0, stream>>>(partial, out,
                                                        nblocks / 4,
                                                        1.0f / (float)n);
    }
}